// Round 13
// baseline (1635.659 us; speedup 1.0000x reference)
//
#include <hip/hip_runtime.h>
#include <cmath>

#define NEG_SLOPE 0.2f
static constexpr int NGRAPH = 64;
static constexpr float H_SCALE = 16.0f;     // h stored as fp8 e4m3 * 16
static constexpr float H_INV_SCALE = 1.0f / 16.0f;

typedef float floatx2 __attribute__((ext_vector_type(2)));

__device__ __forceinline__ float lrelu(float x) {
  return x > 0.f ? x : NEG_SLOPE * x;
}

// device-scope sense-reversing grid barrier. bar[0]=count, bar[1]=generation.
// Requires all blocks co-resident (grid sized via occupancy query on host).
__device__ __forceinline__ void grid_sync(int* bar, int nblk) {
  __syncthreads();
  if (threadIdx.x == 0) {
    __threadfence();
    int g = __hip_atomic_load(&bar[1], __ATOMIC_RELAXED, __HIP_MEMORY_SCOPE_AGENT);
    int a = __hip_atomic_fetch_add(&bar[0], 1, __ATOMIC_ACQ_REL, __HIP_MEMORY_SCOPE_AGENT);
    if (a == nblk - 1) {
      __hip_atomic_store(&bar[0], 0, __ATOMIC_RELAXED, __HIP_MEMORY_SCOPE_AGENT);
      __hip_atomic_fetch_add(&bar[1], 1, __ATOMIC_ACQ_REL, __HIP_MEMORY_SCOPE_AGENT);
    } else {
      while (__hip_atomic_load(&bar[1], __ATOMIC_ACQUIRE, __HIP_MEMORY_SCOPE_AGENT) == g)
        __builtin_amdgcn_s_sleep(8);
    }
    __threadfence();
  }
  __syncthreads();
}

// pack this lane's float (x*16) with 3 neighbors into 4 fp8 bytes; lanes with
// (lane&3)==0 store the dword. Must be called by all 64 lanes (shfl).
__device__ __forceinline__ void store_fp8_row(unsigned char* __restrict__ dst,
                                              float v, int lane) {
  float sv = v * H_SCALE;
  float p1 = __shfl_xor(sv, 1);
  int lo = __builtin_amdgcn_cvt_pk_fp8_f32(sv, p1, 0, false);
  int hi = __shfl_xor(lo, 2);
  if ((lane & 3) == 0) {
    unsigned int u = ((unsigned int)lo & 0xFFFFu) | ((unsigned int)hi << 16);
    *(unsigned int*)(dst + lane) = u;
  }
}

struct MegaArgs {
  const float* x; const int* src; const int* dst; const int* batch;
  const float* W0; const float* as0; const float* ad0; const float* b0;
  const float* Wh; const float* ash; const float* adh; const float* bh;
  const float* Wf; const float* bf; float* out;
  unsigned char* hA; float* hB; float* asb; float* adb;
  int2* rowinfo; int* csr; int2* binEdges;
  float* pool; float* cnt;
  int* bucketCounts; int* bar; int* bucketOffsets; int* bucketCursor;
  int N, E, NB, tile, binBlocks, histBlocks;
};

// ---- hidden-layer transform (wave grid-stride), W column in 64 VGPRs ----
__device__ void dev_transform(const float* __restrict__ hin,
                              const float* __restrict__ W,
                              const float* __restrict__ a_src,
                              const float* __restrict__ a_dst,
                              unsigned char* __restrict__ hout,
                              float* __restrict__ as_,
                              float* __restrict__ ad_,
                              int n_nodes, int lane, int gwave, int nwaves) {
  int head = lane >> 4, ch = lane & 15;
  float wreg[64];
#pragma unroll
  for (int k = 0; k < 64; ++k) wreg[k] = W[k * 64 + lane];
  float asc = a_src[head * 16 + ch];
  float adc = a_dst[head * 16 + ch];
  for (int n = gwave; n < n_nodes; n += nwaves) {
    int nu = __builtin_amdgcn_readfirstlane(n);
    const float* hrow = hin + (size_t)nu * 64;
    float acc = 0.f;
#pragma unroll
    for (int k = 0; k < 64; ++k) acc = fmaf(hrow[k], wreg[k], acc);
    store_fp8_row(hout + (size_t)nu * 64, acc, lane);
    float s = acc * asc, d = acc * adc;
#pragma unroll
    for (int off = 8; off; off >>= 1) {
      s += __shfl_down(s, off, 16);
      d += __shfl_down(d, off, 16);
    }
    if (ch == 0) { as_[nu * 4 + head] = s; ad_[nu * 4 + head] = d; }
  }
}

// ---- parallel chunked fallback for deg>32 (register-slim; R11) ----
__device__ void agg_node_chunked(int node, int row, int deg, int lane, int wv,
                                 int (*__restrict__ lds_s)[64],
                                 float (*__restrict__ lds_w)[4 * 68],
                                 const int* __restrict__ csr,
                                 const float* __restrict__ as_,
                                 const float* __restrict__ ad_,
                                 const unsigned char* __restrict__ h,
                                 const float* __restrict__ bias,
                                 float* __restrict__ hout) {
  const float4 ad4 = *(const float4*)(ad_ + node * 4);
  int grp = lane >> 4;
  int chBase = (lane & 15) * 4;
  int headL = (lane & 15) >> 2;
  const int* sp = &lds_s[wv][0];
  const float* wp = &lds_w[wv][headL * 68];
  float ax = 0.f, ay = 0.f, az = 0.f, aw = 0.f, zacc = 0.f;
  for (int base = 0; base < deg; base += 64) {
    int idx = base + lane;
    int s = 0;
    float w0 = 0.f, w1 = 0.f, w2 = 0.f, w3 = 0.f;
    if (idx < deg) {
      s = csr[row + idx];
      const float4 a4 = *(const float4*)(as_ + s * 4);
      w0 = __expf(lrelu(a4.x + ad4.x));
      w1 = __expf(lrelu(a4.y + ad4.y));
      w2 = __expf(lrelu(a4.z + ad4.z));
      w3 = __expf(lrelu(a4.w + ad4.w));
    }
    lds_s[wv][lane] = s;
    lds_w[wv][0 * 68 + lane] = w0;
    lds_w[wv][1 * 68 + lane] = w1;
    lds_w[wv][2 * 68 + lane] = w2;
    lds_w[wv][3 * 68 + lane] = w3;
    int cnt2 = min(64, deg - base);
    int iters = (cnt2 + 3) >> 2;
    for (int b2 = 0; b2 < iters; b2 += 8) {
      unsigned int g[8];
      float u[8];
#pragma unroll
      for (int k = 0; k < 8; ++k) {
        int it = b2 + k;
        int j = (it * 4 + grp) & 63;
        int sj = sp[j];
        u[k] = (it < iters) ? wp[j] : 0.f;
        g[k] = *(const unsigned int*)(h + (size_t)sj * 64 + chBase);
      }
#pragma unroll
      for (int k = 0; k < 8; ++k) {
        floatx2 f01 = __builtin_amdgcn_cvt_pk_f32_fp8((int)g[k], false);
        floatx2 f23 = __builtin_amdgcn_cvt_pk_f32_fp8((int)g[k], true);
        ax = fmaf(u[k], f01.x, ax);
        ay = fmaf(u[k], f01.y, ay);
        az = fmaf(u[k], f23.x, az);
        aw = fmaf(u[k], f23.y, aw);
        zacc += u[k];
      }
    }
  }
  ax += __shfl_xor(ax, 16); ax += __shfl_xor(ax, 32);
  ay += __shfl_xor(ay, 16); ay += __shfl_xor(ay, 32);
  az += __shfl_xor(az, 16); az += __shfl_xor(az, 32);
  aw += __shfl_xor(aw, 16); aw += __shfl_xor(aw, 32);
  zacc += __shfl_xor(zacc, 16); zacc += __shfl_xor(zacc, 32);
  if (lane < 16) {
    const float4 b4 = *(const float4*)(bias + chBase);
    float rz = H_INV_SCALE / zacc;
    float4 o;
    o.x = ax * rz + b4.x;
    o.y = ay * rz + b4.y;
    o.z = az * rz + b4.z;
    o.w = aw * rz + b4.w;
    *(float4*)(hout + (size_t)node * 64 + chBase) = o;
  }
}

// ---- pair-per-wave aggregate (grid-stride; R8/R11 body) ----
__device__ void dev_aggregate(const int2* __restrict__ rowinfo,
                              const int* __restrict__ csr,
                              const float* __restrict__ as_,
                              const float* __restrict__ ad_,
                              const unsigned char* __restrict__ h,
                              const float* __restrict__ bias,
                              float* __restrict__ hout, int n_nodes,
                              int lane, int wv, int gwave, int nwaves,
                              int (*__restrict__ lds_s)[64],
                              float (*__restrict__ lds_w)[4 * 68]) {
  int npairs = (n_nodes + 1) / 2;
  for (int pair = gwave; pair < npairs; pair += nwaves) {
    int node0 = __builtin_amdgcn_readfirstlane(pair * 2);
    int node1 = node0 + 1;
    if (node1 >= n_nodes) {
      int2 ri = rowinfo[node0];
      agg_node_chunked(node0, ri.x, ri.y, lane, wv, lds_s, lds_w,
                       csr, as_, ad_, h, bias, hout);
      continue;
    }
    const int4 rr = *(const int4*)(rowinfo + node0);  // node0 even, 16B ok
    int row0 = rr.x, deg0 = rr.y, row1 = rr.z, deg1 = rr.w;

    if (deg0 <= 32 && deg1 <= 32) {
      int half = lane >> 5;
      int e = lane & 31;
      int rowh = half ? row1 : row0;
      int degh = half ? deg1 : deg0;
      int nodeh = node0 + half;
      int s = 0;
      if (e < degh) s = csr[rowh + e];
      lds_s[wv][lane] = s;
      int grp = (lane >> 4) & 3;
      int chBase = (lane & 15) * 4;
      int headL = (lane & 15) >> 2;
      const int* sp = &lds_s[wv][0];
      unsigned int g0[8], g1[8];
#pragma unroll
      for (int k = 0; k < 8; ++k) {
        int sj = sp[k * 4 + grp];
        g0[k] = *(const unsigned int*)(h + (size_t)sj * 64 + chBase);
      }
#pragma unroll
      for (int k = 0; k < 8; ++k) {
        int sj = sp[32 + k * 4 + grp];
        g1[k] = *(const unsigned int*)(h + (size_t)sj * 64 + chBase);
      }
      const float4 ad4 = *(const float4*)(ad_ + nodeh * 4);
      float w0 = 0.f, w1 = 0.f, w2 = 0.f, w3 = 0.f;
      if (e < degh) {
        const float4 a4 = *(const float4*)(as_ + s * 4);
        w0 = __expf(lrelu(a4.x + ad4.x));
        w1 = __expf(lrelu(a4.y + ad4.y));
        w2 = __expf(lrelu(a4.z + ad4.z));
        w3 = __expf(lrelu(a4.w + ad4.w));
      }
      lds_w[wv][0 * 68 + lane] = w0;
      lds_w[wv][1 * 68 + lane] = w1;
      lds_w[wv][2 * 68 + lane] = w2;
      lds_w[wv][3 * 68 + lane] = w3;
      const float* wp = &lds_w[wv][headL * 68];
      float a0x = 0.f, a0y = 0.f, a0z = 0.f, a0w = 0.f, z0acc = 0.f;
      float a1x = 0.f, a1y = 0.f, a1z = 0.f, a1w = 0.f, z1acc = 0.f;
#pragma unroll
      for (int k = 0; k < 8; ++k) {
        float u = wp[k * 4 + grp];
        floatx2 f01 = __builtin_amdgcn_cvt_pk_f32_fp8((int)g0[k], false);
        floatx2 f23 = __builtin_amdgcn_cvt_pk_f32_fp8((int)g0[k], true);
        a0x = fmaf(u, f01.x, a0x);
        a0y = fmaf(u, f01.y, a0y);
        a0z = fmaf(u, f23.x, a0z);
        a0w = fmaf(u, f23.y, a0w);
        z0acc += u;
      }
#pragma unroll
      for (int k = 0; k < 8; ++k) {
        float u = wp[32 + k * 4 + grp];
        floatx2 f01 = __builtin_amdgcn_cvt_pk_f32_fp8((int)g1[k], false);
        floatx2 f23 = __builtin_amdgcn_cvt_pk_f32_fp8((int)g1[k], true);
        a1x = fmaf(u, f01.x, a1x);
        a1y = fmaf(u, f01.y, a1y);
        a1z = fmaf(u, f23.x, a1z);
        a1w = fmaf(u, f23.y, a1w);
        z1acc += u;
      }
#pragma unroll
      for (int off = 16; off <= 32; off <<= 1) {
        a0x += __shfl_xor(a0x, off); a0y += __shfl_xor(a0y, off);
        a0z += __shfl_xor(a0z, off); a0w += __shfl_xor(a0w, off);
        z0acc += __shfl_xor(z0acc, off);
        a1x += __shfl_xor(a1x, off); a1y += __shfl_xor(a1y, off);
        a1z += __shfl_xor(a1z, off); a1w += __shfl_xor(a1w, off);
        z1acc += __shfl_xor(z1acc, off);
      }
      if (lane < 32) {
        const float4 b4 = *(const float4*)(bias + chBase);
        float ax = (lane < 16) ? a0x : a1x;
        float ay = (lane < 16) ? a0y : a1y;
        float az = (lane < 16) ? a0z : a1z;
        float aw = (lane < 16) ? a0w : a1w;
        float zz = (lane < 16) ? z0acc : z1acc;
        int nodes = node0 + (lane >> 4);
        float rz = H_INV_SCALE / zz;
        float4 o;
        o.x = ax * rz + b4.x;
        o.y = ay * rz + b4.y;
        o.z = az * rz + b4.z;
        o.w = aw * rz + b4.w;
        *(float4*)(hout + (size_t)nodes * 64 + chBase) = o;
      }
      continue;
    }
    agg_node_chunked(node0, row0, deg0, lane, wv, lds_s, lds_w,
                     csr, as_, ad_, h, bias, hout);
    agg_node_chunked(node1, row1, deg1, lane, wv, lds_s, lds_w,
                     csr, as_, ad_, h, bias, hout);
  }
}

// =================== single fused kernel (normal launch) ====================
__global__ void __launch_bounds__(256, 4) mega_kernel(MegaArgs a) {
  __shared__ int sh_a[256];
  __shared__ int sh_b[256];
  __shared__ int lds_s[4][64];
  __shared__ float lds_w[4][4 * 68];

  const int tid = threadIdx.x;
  const int lane = tid & 63;
  const int wv = tid >> 6;
  const int gthread = blockIdx.x * blockDim.x + tid;
  const int nthreads = gridDim.x * blockDim.x;
  const int gwave = gthread >> 6;
  const int nwaves = nthreads >> 6;
  const int nblocks = gridDim.x;
  int* bar = a.bar;

  // ---- Phase A: [blocks < histBlocks] edge histogram | [rest] t0 transform
  if (blockIdx.x < a.histBlocks) {
    for (int t = blockIdx.x; t < a.binBlocks; t += a.histBlocks) {
      sh_a[tid] = 0;
      __syncthreads();
      int start = t * a.tile;
      int end = min(start + a.tile, a.E);
      for (int e = start + tid; e < end; e += 256)
        atomicAdd(&sh_a[a.dst[e] >> 8], 1);
      __syncthreads();
      if (tid < a.NB && sh_a[tid]) atomicAdd(&a.bucketCounts[tid], sh_a[tid]);
      __syncthreads();
    }
  } else {
    int twave = (((blockIdx.x - a.histBlocks) << 8) + tid) >> 6;
    int tnw = ((nblocks - a.histBlocks) << 8) >> 6;
    int head = lane >> 4, ch = lane & 15;
    float w0 = a.W0[lane];
    float asc = a.as0[head * 16 + ch];
    float adc = a.ad0[head * 16 + ch];
    for (int n = twave; n < a.N; n += tnw) {
      float v = a.x[n] * w0;
      store_fp8_row(a.hA + (size_t)n * 64, v, lane);
      float s = v * asc, d = v * adc;
#pragma unroll
      for (int off = 8; off; off >>= 1) {
        s += __shfl_down(s, off, 16);
        d += __shfl_down(d, off, 16);
      }
      if (ch == 0) { a.asb[n * 4 + head] = s; a.adb[n * 4 + head] = d; }
    }
  }
  grid_sync(bar, nblocks);

  // ---- P2: bucket scan (block 0) ----
  if (blockIdx.x == 0) {
    int v = (tid < a.NB) ? a.bucketCounts[tid] : 0;
    sh_a[tid] = v;
    __syncthreads();
#pragma unroll
    for (int off = 1; off < 256; off <<= 1) {
      int t2 = (tid >= off) ? sh_a[tid - off] : 0;
      __syncthreads();
      sh_a[tid] += t2;
      __syncthreads();
    }
    if (tid < a.NB) {
      int excl = sh_a[tid] - v;
      a.bucketOffsets[tid] = excl;
      a.bucketCursor[tid] = excl;
    }
    if (tid == 0) a.bucketOffsets[a.NB] = sh_a[255];
  }
  grid_sync(bar, nblocks);

  // ---- P3: bucket scatter ----
  for (int t = blockIdx.x; t < a.binBlocks; t += nblocks) {
    sh_a[tid] = 0;
    __syncthreads();
    int start = t * a.tile;
    int end = min(start + a.tile, a.E);
    for (int e = start + tid; e < end; e += 256)
      atomicAdd(&sh_a[a.dst[e] >> 8], 1);
    __syncthreads();
    if (tid < a.NB) {
      int c = sh_a[tid];
      sh_b[tid] = c ? atomicAdd(&a.bucketCursor[tid], c) : 0;
      sh_a[tid] = 0;
    }
    __syncthreads();
    for (int e = start + tid; e < end; e += 256) {
      int b = a.dst[e] >> 8;
      int r = atomicAdd(&sh_a[b], 1);
      a.binEdges[sh_b[b] + r] = make_int2(a.src[e], a.dst[e]);
    }
    __syncthreads();
  }
  grid_sync(bar, nblocks);

  // ---- P4: CSR build (block per bucket, grid-stride) ----
  for (int b = blockIdx.x; b < a.NB; b += nblocks) {
    int n0 = b << 8;
    int nLoc = min(256, a.N - n0);
    int eBase = a.bucketOffsets[b];
    int cntE = a.bucketOffsets[b + 1] - eBase;
    sh_a[tid] = 0;
    __syncthreads();
    for (int i = tid; i < cntE; i += 256)
      atomicAdd(&sh_a[a.binEdges[eBase + i].y - n0], 1);
    __syncthreads();
    int v = (tid < nLoc) ? sh_a[tid] + 1 : 0;  // +1 = self-loop
    sh_b[tid] = v;
    __syncthreads();
#pragma unroll
    for (int off = 1; off < 256; off <<= 1) {
      int t2 = (tid >= off) ? sh_b[tid - off] : 0;
      __syncthreads();
      sh_b[tid] += t2;
      __syncthreads();
    }
    int excl = sh_b[tid] - v;
    __syncthreads();
    if (tid < nLoc) {
      int rowStart = eBase + n0 + excl;
      a.rowinfo[n0 + tid] = make_int2(rowStart, v);
      a.csr[rowStart] = n0 + tid;  // self edge in slot 0
      sh_a[tid] = excl + 1;        // local cursor
    }
    __syncthreads();
    for (int i = tid; i < cntE; i += 256) {
      int2 e = a.binEdges[eBase + i];
      int l = e.y - n0;
      int r = atomicAdd(&sh_a[l], 1);
      a.csr[eBase + n0 + r] = e.x;
    }
    __syncthreads();
  }
  grid_sync(bar, nblocks);

  // ---- layers ----
  dev_aggregate(a.rowinfo, a.csr, a.asb, a.adb, a.hA, a.b0, a.hB, a.N,
                lane, wv, gwave, nwaves, lds_s, lds_w);
  grid_sync(bar, nblocks);
  for (int l = 1; l < 4; ++l) {
    dev_transform(a.hB, a.Wh + (size_t)(l - 1) * 64 * 64,
                  a.ash + (l - 1) * 64, a.adh + (l - 1) * 64,
                  a.hA, a.asb, a.adb, a.N, lane, gwave, nwaves);
    grid_sync(bar, nblocks);
    dev_aggregate(a.rowinfo, a.csr, a.asb, a.adb, a.hA,
                  a.bh + (l - 1) * 64, a.hB, a.N,
                  lane, wv, gwave, nwaves, lds_s, lds_w);
    grid_sync(bar, nblocks);
  }

  // ---- pool (wave per 16 nodes, grid-stride) ----
  {
    int poolWaves = (a.N + 15) / 16;
    for (int w = gwave; w < poolWaves; w += nwaves) {
      int n0 = w * 16;
      int n1 = min(n0 + 16, a.N);
      int gcur = a.batch[n0];
      float acc = 0.f, c_acc = 0.f;
      for (int n = n0; n < n1; ++n) {
        int g = a.batch[n];
        if (g != gcur) {
          atomicAdd(&a.pool[gcur * 64 + lane], acc);
          if (lane == 0) atomicAdd(&a.cnt[gcur], c_acc);
          acc = 0.f; c_acc = 0.f; gcur = g;
        }
        acc += a.hB[(size_t)n * 64 + lane];
        c_acc += 1.f;
      }
      atomicAdd(&a.pool[gcur * 64 + lane], acc);
      if (lane == 0) atomicAdd(&a.cnt[gcur], c_acc);
    }
  }
  grid_sync(bar, nblocks);

  // ---- final ----
  for (int g = blockIdx.x; g < NGRAPH; g += nblocks) {
    int o = tid;
    if (o < 5) {
      float c_g = a.cnt[g];
      c_g = c_g > 1.f ? c_g : 1.f;
      float acc = a.bf[o];
      for (int c = 0; c < 64; ++c)
        acc += (a.pool[g * 64 + c] / c_g) * a.Wf[c * 5 + o];
      a.out[g * 5 + o] = acc;
    }
  }
}

extern "C" void kernel_launch(void* const* d_in, const int* in_sizes, int n_in,
                              void* d_out, int out_size, void* d_ws, size_t ws_size,
                              hipStream_t stream) {
  const int N = in_sizes[0];       // 50000
  const int E = in_sizes[1] / 2;   // 800000
  const int nE = E + N;
  const int NB = (N + 255) >> 8;   // 196

  // workspace layout; pool/cnt/bucketCounts/bar contiguous -> single memset
  float* ws  = (float*)d_ws;
  unsigned char* hA = (unsigned char*)ws;       // N*64 bytes (in N*64-float slot)
  float* hB  = ws + (size_t)N * 64;             // N*64 fp32
  float* asb = hB + (size_t)N * 64;             // N*4
  float* adb = asb + (size_t)N * 4;             // N*4
  int2* rowinfo = (int2*)(adb + (size_t)N * 4); // N int2 (16B-aligned base)
  int* csr     = (int*)(rowinfo + N);           // nE
  int2* binEdges = (int2*)(csr + nE);           // E int2
  float* pool  = (float*)(binEdges + E);        // 64*64
  float* cnt   = pool + NGRAPH * 64;            // 64
  int* bucketCounts  = (int*)(cnt + NGRAPH);    // NB+1
  int* bar           = bucketCounts + NB + 1;   // 2 (barrier count, gen)
  int* bucketOffsets = bar + 2;                 // NB+1
  int* bucketCursor  = bucketOffsets + NB + 1;  // NB

  // grid sized to guaranteed co-residency (required by the software barrier)
  static int maxBlocksPerCU = -1;
  if (maxBlocksPerCU < 0) {
    int mb = 0;
    hipError_t err = hipOccupancyMaxActiveBlocksPerMultiprocessor(&mb, mega_kernel, 256, 0);
    maxBlocksPerCU = (err == hipSuccess && mb > 0) ? mb : 1;
  }
  int GRID = maxBlocksPerCU * 256;
  if (GRID > 1024) GRID = 1024;

  const int TILE = 2048;
  const int binBlocks = (E + TILE - 1) / TILE;  // 391
  int histBlocks = GRID / 2;
  if (histBlocks > binBlocks) histBlocks = binBlocks;

  MegaArgs ma;
  ma.x = (const float*)d_in[0];
  ma.src = (const int*)d_in[1];
  ma.dst = (const int*)d_in[1] + E;
  ma.batch = (const int*)d_in[2];
  ma.W0 = (const float*)d_in[3];
  ma.as0 = (const float*)d_in[4];
  ma.ad0 = (const float*)d_in[5];
  ma.b0 = (const float*)d_in[6];
  ma.Wh = (const float*)d_in[7];
  ma.ash = (const float*)d_in[8];
  ma.adh = (const float*)d_in[9];
  ma.bh = (const float*)d_in[10];
  ma.Wf = (const float*)d_in[11];
  ma.bf = (const float*)d_in[12];
  ma.out = (float*)d_out;
  ma.hA = hA; ma.hB = hB; ma.asb = asb; ma.adb = adb;
  ma.rowinfo = rowinfo; ma.csr = csr; ma.binEdges = binEdges;
  ma.pool = pool; ma.cnt = cnt;
  ma.bucketCounts = bucketCounts; ma.bar = bar;
  ma.bucketOffsets = bucketOffsets; ma.bucketCursor = bucketCursor;
  ma.N = N; ma.E = E; ma.NB = NB; ma.tile = TILE;
  ma.binBlocks = binBlocks; ma.histBlocks = histBlocks;

  // zero pool + cnt + bucketCounts + barrier words in one contiguous memset
  hipMemsetAsync(pool, 0,
                 (size_t)(NGRAPH * 64 + NGRAPH + NB + 1 + 2) * sizeof(int),
                 stream);
  mega_kernel<<<GRID, 256, 0, stream>>>(ma);
}

// Round 14
// 289.428 us; speedup vs baseline: 5.6513x; 5.6513x over previous
//
#include <hip/hip_runtime.h>
#include <cmath>

#define NEG_SLOPE 0.2f
static constexpr int NGRAPH = 64;
static constexpr float H_SCALE = 16.0f;     // h stored as fp8 e4m3 * 16
static constexpr float H_INV_SCALE = 1.0f / 16.0f;

typedef float floatx2 __attribute__((ext_vector_type(2)));

__device__ __forceinline__ float lrelu(float x) {
  return x > 0.f ? x : NEG_SLOPE * x;
}

// pack this lane's float (x*16) with 3 neighbors into 4 fp8 bytes; lanes with
// (lane&3)==0 store the dword. Must be called by all 64 lanes (shfl).
__device__ __forceinline__ void store_fp8_row(unsigned char* __restrict__ dst,
                                              float v, int lane) {
  float sv = v * H_SCALE;
  float p1 = __shfl_xor(sv, 1);
  int lo = __builtin_amdgcn_cvt_pk_fp8_f32(sv, p1, 0, false);
  int hi = __shfl_xor(lo, 2);
  if ((lane & 3) == 0) {
    unsigned int u = ((unsigned int)lo & 0xFFFFu) | ((unsigned int)hi << 16);
    *(unsigned int*)(dst + lane) = u;
  }
}

// ---- fused: [blocks 0..histBlocks) edge-bucket histogram |
//             [histBlocks..) layer-0 transform (Fin = 1) + head dots ----
__global__ void t0_hist_kernel(const float* __restrict__ x,
                               const float* __restrict__ W0,
                               const float* __restrict__ a_src,
                               const float* __restrict__ a_dst,
                               unsigned char* __restrict__ h,
                               float* __restrict__ as_,
                               float* __restrict__ ad_,
                               int n_nodes,
                               const int* __restrict__ dst,
                               int* __restrict__ bucketCounts,
                               int nedge, int nb, int tile, int histBlocks) {
  if (blockIdx.x < (unsigned)histBlocks) {
    __shared__ int hist[256];
    hist[threadIdx.x] = 0;
    __syncthreads();
    int start = blockIdx.x * tile;
    int end = min(start + tile, nedge);
    for (int e = start + threadIdx.x; e < end; e += 256)
      atomicAdd(&hist[dst[e] >> 8], 1);
    __syncthreads();
    if (threadIdx.x < nb && hist[threadIdx.x])
      atomicAdd(&bucketCounts[threadIdx.x], hist[threadIdx.x]);
    return;
  }
  int bid = blockIdx.x - histBlocks;
  int lane = threadIdx.x & 63;
  int wave = (bid * blockDim.x + threadIdx.x) >> 6;
  int nwaves = ((gridDim.x - histBlocks) * blockDim.x) >> 6;
  int head = lane >> 4, ch = lane & 15;
  float w0 = W0[lane];
  float asc = a_src[head * 16 + ch];
  float adc = a_dst[head * 16 + ch];
  for (int n = wave; n < n_nodes; n += nwaves) {
    float v = x[n] * w0;
    store_fp8_row(h + (size_t)n * 64, v, lane);
    float s = v * asc, d = v * adc;
#pragma unroll
    for (int off = 8; off; off >>= 1) {
      s += __shfl_down(s, off, 16);
      d += __shfl_down(d, off, 16);
    }
    if (ch == 0) { as_[n * 4 + head] = s; ad_[n * 4 + head] = d; }
  }
}

// ---- hidden-layer transform: W column in 64 VGPRs; h-row via s_load ----
__global__ void transform_kernel(const float* __restrict__ hin,
                                 const float* __restrict__ W,
                                 const float* __restrict__ a_src,
                                 const float* __restrict__ a_dst,
                                 unsigned char* __restrict__ hout,
                                 float* __restrict__ as_,
                                 float* __restrict__ ad_,
                                 int n_nodes) {
  int lane = threadIdx.x & 63;
  int wave = (blockIdx.x * blockDim.x + threadIdx.x) >> 6;
  int nwaves = (gridDim.x * blockDim.x) >> 6;
  int head = lane >> 4, ch = lane & 15;
  float wreg[64];
#pragma unroll
  for (int k = 0; k < 64; ++k) wreg[k] = W[k * 64 + lane];
  float asc = a_src[head * 16 + ch];
  float adc = a_dst[head * 16 + ch];
  for (int n = wave; n < n_nodes; n += nwaves) {
    int nu = __builtin_amdgcn_readfirstlane(n);
    const float* hrow = hin + (size_t)nu * 64;
    float acc = 0.f;
#pragma unroll
    for (int k = 0; k < 64; ++k) acc = fmaf(hrow[k], wreg[k], acc);
    store_fp8_row(hout + (size_t)nu * 64, acc, lane);
    float s = acc * asc, d = acc * adc;
#pragma unroll
    for (int off = 8; off; off >>= 1) {
      s += __shfl_down(s, off, 16);
      d += __shfl_down(d, off, 16);
    }
    if (ch == 0) { as_[nu * 4 + head] = s; ad_[nu * 4 + head] = d; }
  }
}

// ================= binned CSR build (nodes-per-bucket = 256) ================

__global__ void bucket_scan_kernel(const int* __restrict__ bucketCounts,
                                   int* __restrict__ bucketOffsets,
                                   int* __restrict__ bucketCursor, int nb) {
  __shared__ int tmp[256];
  int tid = threadIdx.x;
  int v = (tid < nb) ? bucketCounts[tid] : 0;
  tmp[tid] = v;
  __syncthreads();
#pragma unroll
  for (int off = 1; off < 256; off <<= 1) {
    int t = (tid >= off) ? tmp[tid - off] : 0;
    __syncthreads();
    tmp[tid] += t;
    __syncthreads();
  }
  if (tid < nb) {
    int excl = tmp[tid] - v;
    bucketOffsets[tid] = excl;
    bucketCursor[tid] = excl;
  }
  if (tid == 0) bucketOffsets[nb] = tmp[255];
}

__global__ void bucket_scatter_kernel(const int* __restrict__ src,
                                      const int* __restrict__ dst,
                                      int* __restrict__ bucketCursor,
                                      int2* __restrict__ binEdges,
                                      int nedge, int nb, int tile) {
  __shared__ int hist[256];
  __shared__ int base[256];
  hist[threadIdx.x] = 0;
  __syncthreads();
  int start = blockIdx.x * tile;
  int end = min(start + tile, nedge);
  for (int e = start + threadIdx.x; e < end; e += 256)
    atomicAdd(&hist[dst[e] >> 8], 1);
  __syncthreads();
  if (threadIdx.x < nb) {
    int c = hist[threadIdx.x];
    base[threadIdx.x] = c ? atomicAdd(&bucketCursor[threadIdx.x], c) : 0;
    hist[threadIdx.x] = 0;
  }
  __syncthreads();
  for (int e = start + threadIdx.x; e < end; e += 256) {
    int b = dst[e] >> 8;
    int r = atomicAdd(&hist[b], 1);
    binEdges[base[b] + r] = make_int2(src[e], dst[e]);
  }
}

__global__ void csr_build_kernel(const int2* __restrict__ binEdges,
                                 const int* __restrict__ bucketOffsets,
                                 int2* __restrict__ rowinfo,
                                 int* __restrict__ csr, int n_nodes) {
  __shared__ int hist[256];
  __shared__ int tmp[256];
  int tid = threadIdx.x;
  int b = blockIdx.x;
  int n0 = b << 8;
  int nLoc = min(256, n_nodes - n0);
  int eBase = bucketOffsets[b];
  int cntE = bucketOffsets[b + 1] - eBase;
  hist[tid] = 0;
  __syncthreads();
  for (int i = tid; i < cntE; i += 256)
    atomicAdd(&hist[binEdges[eBase + i].y - n0], 1);
  __syncthreads();
  int v = (tid < nLoc) ? hist[tid] + 1 : 0;  // +1 = self-loop
  tmp[tid] = v;
  __syncthreads();
#pragma unroll
  for (int off = 1; off < 256; off <<= 1) {
    int t = (tid >= off) ? tmp[tid - off] : 0;
    __syncthreads();
    tmp[tid] += t;
    __syncthreads();
  }
  int excl = tmp[tid] - v;
  __syncthreads();
  if (tid < nLoc) {
    int rowStart = eBase + n0 + excl;
    rowinfo[n0 + tid] = make_int2(rowStart, v);
    csr[rowStart] = n0 + tid;  // self edge in slot 0
    hist[tid] = excl + 1;      // local cursor
  }
  __syncthreads();
  for (int i = tid; i < cntE; i += 256) {
    int2 e = binEdges[eBase + i];
    int l = e.y - n0;
    int r = atomicAdd(&hist[l], 1);
    csr[eBase + n0 + r] = e.x;
  }
}

// ========== fused softmax + weighted gather ==================
// PARALLEL chunked fallback (any deg, register-slim): per 64-edge chunk,
// full-wave csr+as_+exp -> LDS, then 16x4 pipelined fp8 gather. No
// max-subtraction (cancels exactly; e bounded). No serial tail (R10 lesson),
// no fat two-pass registers (keeps kernel <=64 VGPR for 8 waves/SIMD).
__device__ void agg_node_chunked(int node, int row, int deg, int lane, int wv,
                                 int (*__restrict__ lds_s)[64],
                                 float (*__restrict__ lds_w)[4 * 68],
                                 const int* __restrict__ csr,
                                 const float* __restrict__ as_,
                                 const float* __restrict__ ad_,
                                 const unsigned char* __restrict__ h,
                                 const float* __restrict__ bias,
                                 float* __restrict__ hout) {
  const float4 ad4 = *(const float4*)(ad_ + node * 4);
  int grp = lane >> 4;
  int chBase = (lane & 15) * 4;
  int headL = (lane & 15) >> 2;
  const int* sp = &lds_s[wv][0];
  const float* wp = &lds_w[wv][headL * 68];
  float ax = 0.f, ay = 0.f, az = 0.f, aw = 0.f, zacc = 0.f;
  for (int base = 0; base < deg; base += 64) {
    int idx = base + lane;
    int s = 0;
    float w0 = 0.f, w1 = 0.f, w2 = 0.f, w3 = 0.f;
    if (idx < deg) {
      s = csr[row + idx];
      const float4 a4 = *(const float4*)(as_ + s * 4);
      w0 = __expf(lrelu(a4.x + ad4.x));
      w1 = __expf(lrelu(a4.y + ad4.y));
      w2 = __expf(lrelu(a4.z + ad4.z));
      w3 = __expf(lrelu(a4.w + ad4.w));
    }
    lds_s[wv][lane] = s;
    lds_w[wv][0 * 68 + lane] = w0;
    lds_w[wv][1 * 68 + lane] = w1;
    lds_w[wv][2 * 68 + lane] = w2;
    lds_w[wv][3 * 68 + lane] = w3;
    int cnt2 = min(64, deg - base);
    int iters = (cnt2 + 3) >> 2;     // 1..16
    for (int b2 = 0; b2 < iters; b2 += 8) {
      unsigned int g[8];
      float u[8];
#pragma unroll
      for (int k = 0; k < 8; ++k) {
        int it = b2 + k;
        int j = (it * 4 + grp) & 63;   // it<=15 -> no wrap
        int sj = sp[j];
        u[k] = (it < iters) ? wp[j] : 0.f;
        g[k] = *(const unsigned int*)(h + (size_t)sj * 64 + chBase);
      }
#pragma unroll
      for (int k = 0; k < 8; ++k) {
        floatx2 f01 = __builtin_amdgcn_cvt_pk_f32_fp8((int)g[k], false);
        floatx2 f23 = __builtin_amdgcn_cvt_pk_f32_fp8((int)g[k], true);
        ax = fmaf(u[k], f01.x, ax);
        ay = fmaf(u[k], f01.y, ay);
        az = fmaf(u[k], f23.x, az);
        aw = fmaf(u[k], f23.y, aw);
        zacc += u[k];
      }
    }
  }
  ax += __shfl_xor(ax, 16); ax += __shfl_xor(ax, 32);
  ay += __shfl_xor(ay, 16); ay += __shfl_xor(ay, 32);
  az += __shfl_xor(az, 16); az += __shfl_xor(az, 32);
  aw += __shfl_xor(aw, 16); aw += __shfl_xor(aw, 32);
  zacc += __shfl_xor(zacc, 16); zacc += __shfl_xor(zacc, 32);
  if (lane < 16) {
    const float4 b4 = *(const float4*)(bias + chBase);
    float rz = H_INV_SCALE / zacc;
    float4 o;
    o.x = ax * rz + b4.x;
    o.y = ay * rz + b4.y;
    o.z = az * rz + b4.z;
    o.w = aw * rz + b4.w;
    *(float4*)(hout + (size_t)node * 64 + chBase) = o;
  }
}

// wave handles a node PAIR with batched full-width phases: one csr load
// (halves), 16 h-gathers back-to-back (2x MLP), one as_+exp pass, two FMA
// passes. launch_bounds(256,8): <=64 VGPR -> 8 waves/SIMD (latency-bound).
__global__ void __launch_bounds__(256, 8)
aggregate_kernel(const int2* __restrict__ rowinfo,
                 const int* __restrict__ csr,
                 const float* __restrict__ as_,
                 const float* __restrict__ ad_,
                 const unsigned char* __restrict__ h,
                 const float* __restrict__ bias,
                 float* __restrict__ hout, int n_nodes) {
  __shared__ int lds_s[4][64];
  __shared__ float lds_w[4][4 * 68];  // stride 68: conflict-free
  int lane = threadIdx.x & 63;
  int wv = threadIdx.x >> 6;
  int pair = (blockIdx.x * blockDim.x + threadIdx.x) >> 6;
  int node0 = pair * 2;
  if (node0 >= n_nodes) return;
  node0 = __builtin_amdgcn_readfirstlane(node0);  // scalar loads below
  int node1 = node0 + 1;
  if (node1 >= n_nodes) {
    int2 ri = rowinfo[node0];
    agg_node_chunked(node0, ri.x, ri.y, lane, wv, lds_s, lds_w,
                     csr, as_, ad_, h, bias, hout);
    return;
  }
  const int4 rr = *(const int4*)(rowinfo + node0);  // 16B-aligned (node0 even)
  int row0 = rr.x, deg0 = rr.y, row1 = rr.z, deg1 = rr.w;

  if (deg0 <= 32 && deg1 <= 32) {
    // phase 1: one csr load covers both halves; slot = half*32 + e
    int half = lane >> 5;
    int e = lane & 31;
    int rowh = half ? row1 : row0;
    int degh = half ? deg1 : deg0;
    int nodeh = node0 + half;
    int s = 0;
    if (e < degh) s = csr[rowh + e];
    lds_s[wv][lane] = s;            // dead slots -> row 0 (L1-hot)
    int grp = (lane >> 4) & 3;      // 4 edge-groups spread across the wave
    int chBase = (lane & 15) * 4;   // 4 fp8 channels per lane
    int headL = (lane & 15) >> 2;
    const int* sp = &lds_s[wv][0];
    // phase 2: issue ALL 16 h-gathers (8 per node) back-to-back
    unsigned int g0[8], g1[8];
#pragma unroll
    for (int k = 0; k < 8; ++k) {
      int sj = sp[k * 4 + grp];
      g0[k] = *(const unsigned int*)(h + (size_t)sj * 64 + chBase);
    }
#pragma unroll
    for (int k = 0; k < 8; ++k) {
      int sj = sp[32 + k * 4 + grp];
      g1[k] = *(const unsigned int*)(h + (size_t)sj * 64 + chBase);
    }
    // phase 3 (overlaps in-flight loads): as_ gather + exp for both halves
    const float4 ad4 = *(const float4*)(ad_ + nodeh * 4);
    float w0 = 0.f, w1 = 0.f, w2 = 0.f, w3 = 0.f;
    if (e < degh) {
      const float4 a4 = *(const float4*)(as_ + s * 4);
      w0 = __expf(lrelu(a4.x + ad4.x));
      w1 = __expf(lrelu(a4.y + ad4.y));
      w2 = __expf(lrelu(a4.z + ad4.z));
      w3 = __expf(lrelu(a4.w + ad4.w));
    }
    lds_w[wv][0 * 68 + lane] = w0;   // node0 slots 0..31, node1 slots 32..63
    lds_w[wv][1 * 68 + lane] = w1;
    lds_w[wv][2 * 68 + lane] = w2;
    lds_w[wv][3 * 68 + lane] = w3;
    // phase 4: FMA both nodes (full wave each; zero weights mask dead slots)
    const float* wp = &lds_w[wv][headL * 68];
    float a0x = 0.f, a0y = 0.f, a0z = 0.f, a0w = 0.f, z0acc = 0.f;
    float a1x = 0.f, a1y = 0.f, a1z = 0.f, a1w = 0.f, z1acc = 0.f;
#pragma unroll
    for (int k = 0; k < 8; ++k) {
      float u = wp[k * 4 + grp];
      floatx2 f01 = __builtin_amdgcn_cvt_pk_f32_fp8((int)g0[k], false);
      floatx2 f23 = __builtin_amdgcn_cvt_pk_f32_fp8((int)g0[k], true);
      a0x = fmaf(u, f01.x, a0x);
      a0y = fmaf(u, f01.y, a0y);
      a0z = fmaf(u, f23.x, a0z);
      a0w = fmaf(u, f23.y, a0w);
      z0acc += u;
    }
#pragma unroll
    for (int k = 0; k < 8; ++k) {
      float u = wp[32 + k * 4 + grp];
      floatx2 f01 = __builtin_amdgcn_cvt_pk_f32_fp8((int)g1[k], false);
      floatx2 f23 = __builtin_amdgcn_cvt_pk_f32_fp8((int)g1[k], true);
      a1x = fmaf(u, f01.x, a1x);
      a1y = fmaf(u, f01.y, a1y);
      a1z = fmaf(u, f23.x, a1z);
      a1w = fmaf(u, f23.y, a1w);
      z1acc += u;
    }
    // combine the 4 edge-groups (lanes L, L^16, L^32, L^48) for both nodes
#pragma unroll
    for (int off = 16; off <= 32; off <<= 1) {
      a0x += __shfl_xor(a0x, off); a0y += __shfl_xor(a0y, off);
      a0z += __shfl_xor(a0z, off); a0w += __shfl_xor(a0w, off);
      z0acc += __shfl_xor(z0acc, off);
      a1x += __shfl_xor(a1x, off); a1y += __shfl_xor(a1y, off);
      a1z += __shfl_xor(a1z, off); a1w += __shfl_xor(a1w, off);
      z1acc += __shfl_xor(z1acc, off);
    }
    if (lane < 32) {
      const float4 b4 = *(const float4*)(bias + chBase);
      float ax = (lane < 16) ? a0x : a1x;
      float ay = (lane < 16) ? a0y : a1y;
      float az = (lane < 16) ? a0z : a1z;
      float aw = (lane < 16) ? a0w : a1w;
      float zz = (lane < 16) ? z0acc : z1acc;
      int nodes = node0 + (lane >> 4);
      float rz = H_INV_SCALE / zz;
      float4 o;
      o.x = ax * rz + b4.x;
      o.y = ay * rz + b4.y;
      o.z = az * rz + b4.z;
      o.w = aw * rz + b4.w;
      *(float4*)(hout + (size_t)nodes * 64 + chBase) = o;
    }
    return;
  }

  // fallback: per-node PARALLEL chunked path (rare; register-slim)
  agg_node_chunked(node0, row0, deg0, lane, wv, lds_s, lds_w,
                   csr, as_, ad_, h, bias, hout);
  agg_node_chunked(node1, row1, deg1, lane, wv, lds_s, lds_w,
                   csr, as_, ad_, h, bias, hout);
}

// =============================== pooling ====================================

// wave per 16 nodes; batch sorted -> one atomic per segment boundary
__global__ void pool_kernel(const float* __restrict__ h,
                            const int* __restrict__ batch,
                            float* __restrict__ pool,
                            float* __restrict__ cnt, int n_nodes) {
  int lane = threadIdx.x & 63;
  int wave = (blockIdx.x * blockDim.x + threadIdx.x) >> 6;
  int n0 = wave * 16;
  if (n0 >= n_nodes) return;
  int n1 = min(n0 + 16, n_nodes);
  int gcur = batch[n0];
  float acc = 0.f, c_acc = 0.f;
  for (int n = n0; n < n1; ++n) {
    int g = batch[n];
    if (g != gcur) {
      atomicAdd(&pool[gcur * 64 + lane], acc);
      if (lane == 0) atomicAdd(&cnt[gcur], c_acc);
      acc = 0.f; c_acc = 0.f; gcur = g;
    }
    acc += h[(size_t)n * 64 + lane];
    c_acc += 1.f;
  }
  atomicAdd(&pool[gcur * 64 + lane], acc);
  if (lane == 0) atomicAdd(&cnt[gcur], c_acc);
}

__global__ void final_kernel(const float* __restrict__ pool,
                             const float* __restrict__ cnt,
                             const float* __restrict__ Wf,
                             const float* __restrict__ bf,
                             float* __restrict__ out) {
  int g = blockIdx.x;
  int o = threadIdx.x;
  if (o >= 5) return;
  float cg = cnt[g];
  cg = cg > 1.f ? cg : 1.f;
  float acc = bf[o];
  for (int c = 0; c < 64; ++c)
    acc += (pool[g * 64 + c] / cg) * Wf[c * 5 + o];
  out[g * 5 + o] = acc;
}

extern "C" void kernel_launch(void* const* d_in, const int* in_sizes, int n_in,
                              void* d_out, int out_size, void* d_ws, size_t ws_size,
                              hipStream_t stream) {
  const float* x     = (const float*)d_in[0];
  const int*   ei    = (const int*)d_in[1];
  const int*   batch = (const int*)d_in[2];
  const float* W0    = (const float*)d_in[3];
  const float* as0   = (const float*)d_in[4];
  const float* ad0   = (const float*)d_in[5];
  const float* b0    = (const float*)d_in[6];
  const float* Wh    = (const float*)d_in[7];
  const float* ash   = (const float*)d_in[8];
  const float* adh   = (const float*)d_in[9];
  const float* bh    = (const float*)d_in[10];
  const float* Wf    = (const float*)d_in[11];
  const float* bf    = (const float*)d_in[12];
  float* out = (float*)d_out;

  const int N = in_sizes[0];       // 50000
  const int E = in_sizes[1] / 2;   // 800000
  const int* src = ei;
  const int* dst = ei + E;
  const int nE = E + N;
  const int NB = (N + 255) >> 8;   // buckets of 256 nodes (196)

  // workspace layout (pool/cnt/bucketCounts contiguous -> single memset)
  float* ws  = (float*)d_ws;
  unsigned char* hA = (unsigned char*)ws;       // N*64 bytes (in N*64-float slot)
  float* hB  = ws + (size_t)N * 64;             // N*64 fp32
  float* asb = hB + (size_t)N * 64;             // N*4
  float* adb = asb + (size_t)N * 4;             // N*4
  int2* rowinfo = (int2*)(adb + (size_t)N * 4); // N int2 (16B-aligned base)
  int* csr     = (int*)(rowinfo + N);           // nE
  int2* binEdges = (int2*)(csr + nE);           // E int2
  float* pool  = (float*)(binEdges + E);        // 64*64
  float* cnt   = pool + NGRAPH * 64;            // 64
  int* bucketCounts  = (int*)(cnt + NGRAPH);    // NB+1
  int* bucketOffsets = bucketCounts + NB + 1;   // NB+1
  int* bucketCursor  = bucketOffsets + NB + 1;  // NB

  const int TILE = 2048;
  const int binBlocks = (E + TILE - 1) / TILE;
  const int pairWaves = (N + 1) / 2;            // 2 nodes per wave
  const int pairBlocks = (pairWaves + 3) / 4;
  const int poolWaves = (N + 15) / 16;
  const int poolBlocks = (poolWaves + 3) / 4;

  // zero pool + cnt + bucketCounts in one contiguous async memset
  hipMemsetAsync(pool, 0, (size_t)(NGRAPH * 64 + NGRAPH + NB + 1) * sizeof(int), stream);
  // fused layer-0 transform + bucket histogram
  t0_hist_kernel<<<binBlocks + 2048, 256, 0, stream>>>(x, W0, as0, ad0, hA, asb, adb, N,
                                                       dst, bucketCounts, E, NB, TILE, binBlocks);
  bucket_scan_kernel<<<1, 256, 0, stream>>>(bucketCounts, bucketOffsets, bucketCursor, NB);
  bucket_scatter_kernel<<<binBlocks, 256, 0, stream>>>(src, dst, bucketCursor, binEdges, E, NB, TILE);
  csr_build_kernel<<<NB, 256, 0, stream>>>(binEdges, bucketOffsets, rowinfo, csr, N);

  for (int layer = 0; layer < 4; ++layer) {
    if (layer > 0) {
      transform_kernel<<<2048, 256, 0, stream>>>(hB, Wh + (size_t)(layer - 1) * 64 * 64,
                                                 ash + (layer - 1) * 64, adh + (layer - 1) * 64,
                                                 hA, asb, adb, N);
    }
    const float* bias = (layer == 0) ? b0 : (bh + (layer - 1) * 64);
    aggregate_kernel<<<pairBlocks, 256, 0, stream>>>(rowinfo, csr,
                                                     asb, adb, hA, bias, hB, N);
  }

  pool_kernel<<<poolBlocks, 256, 0, stream>>>(hB, batch, pool, cnt, N);
  final_kernel<<<NGRAPH, 64, 0, stream>>>(pool, cnt, Wf, bf, out);
}